// Round 1
// baseline (712.713 us; speedup 1.0000x reference)
//
#include <hip/hip_runtime.h>
#include <hip/hip_bf16.h>

typedef __bf16 bf16x8 __attribute__((ext_vector_type(8)));
typedef float f32x4 __attribute__((ext_vector_type(4)));

#define MFMA16(A, B, C) __builtin_amdgcn_mfma_f32_16x16x32_bf16(A, B, C, 0, 0, 0)

// ---------------------------------------------------------------------------
// Weight transpose + fp32->bf16:  W[K,N] fp32  ->  Wt[N,K] bf16
// block (32,8), grid (N/32, K/32)
// ---------------------------------------------------------------------------
__global__ __launch_bounds__(256) void wt_transpose(const float* __restrict__ W,
                                                    __hip_bfloat16* __restrict__ Wt,
                                                    int K, int N) {
    __shared__ float tile[32][33];
    const int bn = blockIdx.x * 32;
    const int bk = blockIdx.y * 32;
    const int tx = threadIdx.x, ty = threadIdx.y;
#pragma unroll
    for (int i = 0; i < 4; i++) {
        tile[ty + i * 8][tx] = W[(size_t)(bk + ty + i * 8) * N + bn + tx];
    }
    __syncthreads();
#pragma unroll
    for (int i = 0; i < 4; i++) {
        Wt[(size_t)(bn + ty + i * 8) * K + bk + tx] = __float2bfloat16(tile[tx][ty + i * 8]);
    }
}

// ---------------------------------------------------------------------------
// fp32 -> bf16 elementwise, 4 elems/thread
// ---------------------------------------------------------------------------
__global__ __launch_bounds__(256) void to_bf16(const float* __restrict__ x,
                                               __hip_bfloat16* __restrict__ y, int n) {
    const int i = (blockIdx.x * 256 + threadIdx.x) * 4;
    if (i >= n) return;
    const float4 v = *(const float4*)(x + i);
    __align__(8) __hip_bfloat16 t[4] = {__float2bfloat16(v.x), __float2bfloat16(v.y),
                                        __float2bfloat16(v.z), __float2bfloat16(v.w)};
    *(uint2*)(y + i) = *(const uint2*)t;
}

// ---------------------------------------------------------------------------
// GEMM: C[M,N] = A[M,K](bf16) @ Bt[N,K]^T(bf16) + bias(f32)
// 128x128 block tile, 4 waves (2x2 of 64x64), BK=32 (one MFMA k-step)
// ---------------------------------------------------------------------------
__global__ __launch_bounds__(256) void gemm_bias_kernel(
    const __hip_bfloat16* __restrict__ A, const __hip_bfloat16* __restrict__ Bt,
    const float* __restrict__ bias, float* __restrict__ Cf,
    __hip_bfloat16* __restrict__ Cb, int M, int N, int K) {
    constexpr int LDA = 40;  // 32 + 8 pad: breaks 2-bank aliasing on frag reads
    __shared__ __align__(16) __hip_bfloat16 As[128 * LDA];
    __shared__ __align__(16) __hip_bfloat16 Bs[128 * LDA];
    const int tid = threadIdx.x;
    const int wave = tid >> 6, lane = tid & 63;
    const int quad = lane >> 4, l16 = lane & 15;
    const int m0 = blockIdx.x * 128, n0 = blockIdx.y * 128;
    const int wm = (wave & 1) * 64, wn = (wave >> 1) * 64;
    const int srow = tid >> 2, scol = (tid & 3) * 8;
    f32x4 acc[4][4] = {};
    for (int k0 = 0; k0 < K; k0 += 32) {
        __syncthreads();
        {
            const uint4 a0 = *(const uint4*)(A + (size_t)(m0 + srow) * K + k0 + scol);
            const uint4 a1 = *(const uint4*)(A + (size_t)(m0 + srow + 64) * K + k0 + scol);
            const uint4 b0 = *(const uint4*)(Bt + (size_t)(n0 + srow) * K + k0 + scol);
            const uint4 b1 = *(const uint4*)(Bt + (size_t)(n0 + srow + 64) * K + k0 + scol);
            *(uint4*)(&As[srow * LDA + scol]) = a0;
            *(uint4*)(&As[(srow + 64) * LDA + scol]) = a1;
            *(uint4*)(&Bs[srow * LDA + scol]) = b0;
            *(uint4*)(&Bs[(srow + 64) * LDA + scol]) = b1;
        }
        __syncthreads();
        bf16x8 af[4], bfr[4];
#pragma unroll
        for (int i = 0; i < 4; i++) {
            af[i] = *(const bf16x8*)(&As[(wm + i * 16 + l16) * LDA + quad * 8]);
            bfr[i] = *(const bf16x8*)(&Bs[(wn + i * 16 + l16) * LDA + quad * 8]);
        }
#pragma unroll
        for (int i = 0; i < 4; i++)
#pragma unroll
            for (int j = 0; j < 4; j++)
                acc[i][j] = MFMA16(af[i], bfr[j], acc[i][j]);
    }
    // epilogue: C row = quad*4+reg, col = l16
#pragma unroll
    for (int i = 0; i < 4; i++) {
#pragma unroll
        for (int j = 0; j < 4; j++) {
            const int mr = m0 + wm + i * 16 + quad * 4;
            const int nc = n0 + wn + j * 16 + l16;
            const float bv = bias[nc];
#pragma unroll
            for (int r = 0; r < 4; r++) {
                const float v = acc[i][j][r] + bv;
                const size_t idx = (size_t)(mr + r) * N + nc;
                if (Cf) Cf[idx] = v;
                if (Cb) Cb[idx] = __float2bfloat16(v);
            }
        }
    }
}

// ---------------------------------------------------------------------------
// Flash attention, bf16 MFMA. Block = 4 waves; each wave owns 16 q-rows.
// Q/K/V layouts: elem(t,b,h,d) at base + t*stride (strides parameterized so
// fused QKV / KV buffers work). O is fp32 [T*B, 1024].
// ---------------------------------------------------------------------------
__global__ __launch_bounds__(256) void attn_kernel(
    const __hip_bfloat16* __restrict__ Qp, const __hip_bfloat16* __restrict__ Kp,
    const __hip_bfloat16* __restrict__ Vp, float* __restrict__ Op,
    int T, int Bb, int qRS, int kvRS, int causal) {
    constexpr int LDT = 72;  // 64 + 8 pad
    __shared__ __align__(16) __hip_bfloat16 Ks[64 * LDT];      // [key][d]
    __shared__ __align__(16) __hip_bfloat16 Vs[64 * LDT];      // [d][key] (transposed)
    __shared__ __align__(16) __hip_bfloat16 Ps[4][16 * LDT];   // per-wave P [row][key]
    const int tid = threadIdx.x, wave = tid >> 6, lane = tid & 63;
    const int quad = lane >> 4, l16 = lane & 15;
    const int bh = blockIdx.y;
    const int b = bh % Bb;
    const int h = bh / Bb;
    const int q0 = blockIdx.x * 64;
    const size_t qbase = (size_t)b * qRS + h * 64;
    const size_t kbase = (size_t)b * kvRS + h * 64;
    const int qstride = Bb * qRS, kstride = Bb * kvRS;
    const size_t obase = (size_t)b * 1024 + h * 64;
    const int ostride = Bb * 1024;

    bf16x8 qf0, qf1;
    {
        const __hip_bfloat16* qptr = Qp + qbase + (size_t)(q0 + wave * 16 + l16) * qstride;
        qf0 = *(const bf16x8*)(qptr + quad * 8);
        qf1 = *(const bf16x8*)(qptr + 32 + quad * 8);
    }
    float m_i[4], l_i[4];
    f32x4 o[4] = {};
#pragma unroll
    for (int r = 0; r < 4; r++) { m_i[r] = -1e30f; l_i[r] = 0.f; }

    const int myq = q0 + wave * 16 + quad * 4;  // + r
    const int kend = causal ? (q0 + 64) : T;
    for (int k0 = 0; k0 < kend; k0 += 64) {
        __syncthreads();  // protect prior-iteration Ks/Vs reads
        {
            const int key = tid >> 2, dd = (tid & 3) * 16;
            const __hip_bfloat16* kp2 = Kp + kbase + (size_t)(k0 + key) * kstride + dd;
            const uint4 k0v = *(const uint4*)(kp2);
            const uint4 k1v = *(const uint4*)(kp2 + 8);
            *(uint4*)(&Ks[key * LDT + dd]) = k0v;
            *(uint4*)(&Ks[key * LDT + dd + 8]) = k1v;
            const __hip_bfloat16* vp2 = Vp + kbase + (size_t)(k0 + key) * kstride + dd;
            const uint4 v0v = *(const uint4*)(vp2);
            const uint4 v1v = *(const uint4*)(vp2 + 8);
            __align__(16) __hip_bfloat16 tmp[16];
            *(uint4*)(tmp) = v0v;
            *(uint4*)(tmp + 8) = v1v;
#pragma unroll
            for (int j = 0; j < 16; j++) Vs[(dd + j) * LDT + key] = tmp[j];
        }
        __syncthreads();
        // S = Q @ K^T  (4 key-subtiles of 16)
        f32x4 s[4];
#pragma unroll
        for (int n = 0; n < 4; n++) {
            f32x4 z = {};
            const bf16x8 kf0 = *(const bf16x8*)(&Ks[(n * 16 + l16) * LDT + quad * 8]);
            const bf16x8 kf1 = *(const bf16x8*)(&Ks[(n * 16 + l16) * LDT + 32 + quad * 8]);
            z = MFMA16(qf0, kf0, z);
            z = MFMA16(qf1, kf1, z);
            s[n] = z;
        }
        // scale + causal mask + row max (rows live on 16 lanes of same quad)
        float rmax[4] = {-1e30f, -1e30f, -1e30f, -1e30f};
#pragma unroll
        for (int n = 0; n < 4; n++) {
            const int key = k0 + n * 16 + l16;
#pragma unroll
            for (int r = 0; r < 4; r++) {
                float sv = s[n][r] * 0.125f;
                if (causal && key > myq + r) sv = -1e30f;
                s[n][r] = sv;
                rmax[r] = fmaxf(rmax[r], sv);
            }
        }
#pragma unroll
        for (int r = 0; r < 4; r++) {
            float v = rmax[r];
            v = fmaxf(v, __shfl_xor(v, 1, 16));
            v = fmaxf(v, __shfl_xor(v, 2, 16));
            v = fmaxf(v, __shfl_xor(v, 4, 16));
            v = fmaxf(v, __shfl_xor(v, 8, 16));
            rmax[r] = v;
        }
        float alpha[4], rsum[4] = {0.f, 0.f, 0.f, 0.f};
#pragma unroll
        for (int r = 0; r < 4; r++) {
            const float mnew = fmaxf(m_i[r], rmax[r]);
            alpha[r] = __expf(m_i[r] - mnew);
            m_i[r] = mnew;
        }
#pragma unroll
        for (int n = 0; n < 4; n++) {
#pragma unroll
            for (int r = 0; r < 4; r++) {
                const float pv = __expf(s[n][r] - m_i[r]);
                rsum[r] += pv;
                Ps[wave][(quad * 4 + r) * LDT + n * 16 + l16] = __float2bfloat16(pv);
            }
        }
#pragma unroll
        for (int r = 0; r < 4; r++) {
            float v = rsum[r];
            v += __shfl_xor(v, 1, 16);
            v += __shfl_xor(v, 2, 16);
            v += __shfl_xor(v, 4, 16);
            v += __shfl_xor(v, 8, 16);
            l_i[r] = l_i[r] * alpha[r] + v;
#pragma unroll
            for (int j = 0; j < 4; j++) o[j][r] *= alpha[r];
        }
        __syncthreads();  // P visibility (C-layout writers -> A-layout readers)
        // O += P @ V
        const bf16x8 pf0 = *(const bf16x8*)(&Ps[wave][l16 * LDT + quad * 8]);
        const bf16x8 pf1 = *(const bf16x8*)(&Ps[wave][l16 * LDT + 32 + quad * 8]);
#pragma unroll
        for (int j = 0; j < 4; j++) {
            const bf16x8 vf0 = *(const bf16x8*)(&Vs[(j * 16 + l16) * LDT + quad * 8]);
            const bf16x8 vf1 = *(const bf16x8*)(&Vs[(j * 16 + l16) * LDT + 32 + quad * 8]);
            o[j] = MFMA16(pf0, vf0, o[j]);
            o[j] = MFMA16(pf1, vf1, o[j]);
        }
    }
#pragma unroll
    for (int j = 0; j < 4; j++) {
#pragma unroll
        for (int r = 0; r < 4; r++) {
            Op[obase + (size_t)(myq + r) * ostride + j * 16 + l16] = o[j][r] / l_i[r];
        }
    }
}

// ---------------------------------------------------------------------------
// Fused residual + LayerNorm over D=1024. One block per row (256 thr x 4 elems).
// outf fp32 (required), outb bf16 (optional copy for next GEMM input).
// ---------------------------------------------------------------------------
__global__ __launch_bounds__(256) void ln_res_kernel(
    const float* __restrict__ a, const float* __restrict__ bres,
    const float* __restrict__ g, const float* __restrict__ be,
    float* __restrict__ outf, __hip_bfloat16* __restrict__ outb) {
    const int row = blockIdx.x;
    const int tid = threadIdx.x;
    const size_t off = (size_t)row * 1024 + tid * 4;
    const float4 va = *(const float4*)(a + off);
    const float4 vb = *(const float4*)(bres + off);
    float x0 = va.x + vb.x, x1 = va.y + vb.y, x2 = va.z + vb.z, x3 = va.w + vb.w;
    float s = x0 + x1 + x2 + x3;
    float ss = x0 * x0 + x1 * x1 + x2 * x2 + x3 * x3;
#pragma unroll
    for (int w = 32; w >= 1; w >>= 1) {
        s += __shfl_xor(s, w);
        ss += __shfl_xor(ss, w);
    }
    __shared__ float sm[4], sv[4];
    const int wave = tid >> 6;
    if ((tid & 63) == 0) { sm[wave] = s; sv[wave] = ss; }
    __syncthreads();
    s = sm[0] + sm[1] + sm[2] + sm[3];
    ss = sv[0] + sv[1] + sv[2] + sv[3];
    const float mean = s * (1.f / 1024.f);
    const float inv = rsqrtf(ss * (1.f / 1024.f) - mean * mean + 1e-5f);
    const float4 gg = *(const float4*)(g + tid * 4);
    const float4 bb = *(const float4*)(be + tid * 4);
    const float y0 = (x0 - mean) * inv * gg.x + bb.x;
    const float y1 = (x1 - mean) * inv * gg.y + bb.y;
    const float y2 = (x2 - mean) * inv * gg.z + bb.z;
    const float y3 = (x3 - mean) * inv * gg.w + bb.w;
    *(float4*)(outf + off) = make_float4(y0, y1, y2, y3);
    if (outb) {
        __align__(8) __hip_bfloat16 t[4] = {__float2bfloat16(y0), __float2bfloat16(y1),
                                            __float2bfloat16(y2), __float2bfloat16(y3)};
        *(uint2*)(outb + off) = *(const uint2*)t;
    }
}

// ---------------------------------------------------------------------------
extern "C" void kernel_launch(void* const* d_in, const int* in_sizes, int n_in,
                              void* d_out, int out_size, void* d_ws, size_t ws_size,
                              hipStream_t stream) {
    const float* enc = (const float*)d_in[0];
    const float* dec = (const float*)d_in[1];
    const float* Wq1 = (const float*)d_in[2];
    const float* bq1 = (const float*)d_in[3];
    const float* Wk1 = (const float*)d_in[4];
    const float* bk1 = (const float*)d_in[5];
    const float* Wv1 = (const float*)d_in[6];
    const float* bv1 = (const float*)d_in[7];
    const float* Wq2 = (const float*)d_in[8];
    const float* bq2 = (const float*)d_in[9];
    const float* Wk2 = (const float*)d_in[10];
    const float* bk2 = (const float*)d_in[11];
    const float* Wv2 = (const float*)d_in[12];
    const float* bv2 = (const float*)d_in[13];
    const float* Wl = (const float*)d_in[14];
    const float* bl = (const float*)d_in[15];
    const float* g1 = (const float*)d_in[16];
    const float* be1 = (const float*)d_in[17];
    const float* g2 = (const float*)d_in[18];
    const float* be2 = (const float*)d_in[19];
    const float* g3 = (const float*)d_in[20];
    const float* be3 = (const float*)d_in[21];
    float* outp = (float*)d_out;

    char* p = (char*)d_ws;
    auto alloc = [&](size_t n) {
        char* r = p;
        p += (n + 255) & ~(size_t)255;
        return r;
    };
    const size_t MD = (size_t)8192 * 1024;
    __hip_bfloat16* enc_b = (__hip_bfloat16*)alloc(MD * 2);
    __hip_bfloat16* dec_b = (__hip_bfloat16*)alloc(MD * 2);
    __hip_bfloat16* Wt = (__hip_bfloat16*)alloc((size_t)7 * 1024 * 1024 * 2);
    float* bcat = (float*)alloc((3072 + 2048) * sizeof(float));
    __hip_bfloat16* qkv = (__hip_bfloat16*)alloc(MD * 3 * 2);  // also reused as KV2 [M,2048]
    __hip_bfloat16* qb = (__hip_bfloat16*)alloc(MD * 2);
    float* attnf = (float*)alloc(MD * 4);  // attn1 out -> attn2 out -> z
    float* xf = (float*)alloc(MD * 4);
    float* yf = (float*)alloc(MD * 4);
    __hip_bfloat16* xb = dec_b;  // dec_b dead after QKV1 gemm
    __hip_bfloat16* yb = enc_b;  // enc_b dead after KV2 gemm

    // weight transpose to bf16 [N,K]; order: q1,k1,v1,q2,k2,v2,l
    const float* Ws[7] = {Wq1, Wk1, Wv1, Wq2, Wk2, Wv2, Wl};
    for (int i = 0; i < 7; i++) {
        wt_transpose<<<dim3(32, 32), dim3(32, 8), 0, stream>>>(
            Ws[i], Wt + (size_t)i * 1024 * 1024, 1024, 1024);
    }
    to_bf16<<<8192, 256, 0, stream>>>(enc, enc_b, (int)MD);
    to_bf16<<<8192, 256, 0, stream>>>(dec, dec_b, (int)MD);
    // concatenated biases for fused GEMMs
    hipMemcpyAsync(bcat, bq1, 4096, hipMemcpyDeviceToDevice, stream);
    hipMemcpyAsync(bcat + 1024, bk1, 4096, hipMemcpyDeviceToDevice, stream);
    hipMemcpyAsync(bcat + 2048, bv1, 4096, hipMemcpyDeviceToDevice, stream);
    hipMemcpyAsync(bcat + 3072, bk2, 4096, hipMemcpyDeviceToDevice, stream);
    hipMemcpyAsync(bcat + 4096, bv2, 4096, hipMemcpyDeviceToDevice, stream);

    // --- self-attention ---
    gemm_bias_kernel<<<dim3(64, 24), 256, 0, stream>>>(dec_b, Wt, bcat, nullptr, qkv,
                                                       8192, 3072, 1024);
    attn_kernel<<<dim3(16, 128), 256, 0, stream>>>(qkv, qkv + 1024, qkv + 2048, attnf,
                                                   1024, 8, 3072, 3072, 1);
    ln_res_kernel<<<8192, 256, 0, stream>>>(attnf, dec, g1, be1, xf, xb);

    // --- cross-attention ---
    gemm_bias_kernel<<<dim3(64, 8), 256, 0, stream>>>(
        xb, Wt + (size_t)3 * 1024 * 1024, bq2, nullptr, qb, 8192, 1024, 1024);
    gemm_bias_kernel<<<dim3(64, 16), 256, 0, stream>>>(
        enc_b, Wt + (size_t)4 * 1024 * 1024, bcat + 3072, nullptr, qkv, 8192, 2048, 1024);
    attn_kernel<<<dim3(16, 128), 256, 0, stream>>>(qb, qkv, qkv + 1024, attnf,
                                                   1024, 8, 1024, 2048, 0);
    ln_res_kernel<<<8192, 256, 0, stream>>>(attnf, xf, g2, be2, yf, yb);

    // --- position-wise linear ---
    gemm_bias_kernel<<<dim3(64, 8), 256, 0, stream>>>(
        yb, Wt + (size_t)6 * 1024 * 1024, bl, attnf, nullptr, 8192, 1024, 1024);
    ln_res_kernel<<<8192, 256, 0, stream>>>(attnf, yf, g3, be3, outp, nullptr);
}

// Round 2
// 602.130 us; speedup vs baseline: 1.1837x; 1.1837x over previous
//
#include <hip/hip_runtime.h>
#include <hip/hip_bf16.h>

typedef __bf16 bf16x8 __attribute__((ext_vector_type(8)));
typedef float f32x4 __attribute__((ext_vector_type(4)));

#define MFMA16(A, B, C) __builtin_amdgcn_mfma_f32_16x16x32_bf16(A, B, C, 0, 0, 0)

// async global->LDS, 16B per lane. LDS dest = uniform base + lane*16B.
#define GLDS(gp, lp)                                                              \
    __builtin_amdgcn_global_load_lds(                                             \
        (const __attribute__((address_space(1))) void*)(gp),                      \
        (__attribute__((address_space(3))) void*)(lp), 16, 0, 0)

// ---------------------------------------------------------------------------
// Weight transpose + fp32->bf16:  W[K,N] fp32  ->  Wt[N,K] bf16
// ---------------------------------------------------------------------------
__global__ __launch_bounds__(256) void wt_transpose(const float* __restrict__ W,
                                                    __hip_bfloat16* __restrict__ Wt,
                                                    int K, int N) {
    __shared__ float tile[32][33];
    const int bn = blockIdx.x * 32;
    const int bk = blockIdx.y * 32;
    const int tx = threadIdx.x, ty = threadIdx.y;
#pragma unroll
    for (int i = 0; i < 4; i++) {
        tile[ty + i * 8][tx] = W[(size_t)(bk + ty + i * 8) * N + bn + tx];
    }
    __syncthreads();
#pragma unroll
    for (int i = 0; i < 4; i++) {
        Wt[(size_t)(bn + ty + i * 8) * K + bk + tx] = __float2bfloat16(tile[tx][ty + i * 8]);
    }
}

__global__ __launch_bounds__(256) void to_bf16(const float* __restrict__ x,
                                               __hip_bfloat16* __restrict__ y, int n) {
    const int i = (blockIdx.x * 256 + threadIdx.x) * 4;
    if (i >= n) return;
    const float4 v = *(const float4*)(x + i);
    __align__(8) __hip_bfloat16 t[4] = {__float2bfloat16(v.x), __float2bfloat16(v.y),
                                        __float2bfloat16(v.z), __float2bfloat16(v.w)};
    *(uint2*)(y + i) = *(const uint2*)t;
}

// ---------------------------------------------------------------------------
// GEMM (m97 structure): C[M,N] = A[M,K] @ Bt[N,K]^T + bias, bf16 in, MFMA.
// 128x128 tile, 4 waves 2x2, BK=32, global_load_lds dwordx4, unpadded LDS.
// ---------------------------------------------------------------------------
__global__ __launch_bounds__(256) void gemm_bias_kernel(
    const __hip_bfloat16* __restrict__ A, const __hip_bfloat16* __restrict__ Bt,
    const float* __restrict__ bias, float* __restrict__ Cf,
    __hip_bfloat16* __restrict__ Cb, int M, int N, int K) {
    __shared__ __align__(16) __hip_bfloat16 As[128 * 32];  // row-major, 32 bf16/row
    __shared__ __align__(16) __hip_bfloat16 Bs[128 * 32];
    const int tid = threadIdx.x;
    const int wave = tid >> 6, lane = tid & 63;
    const int quad = lane >> 4, l16 = lane & 15;
    const int m0 = blockIdx.x * 128, n0 = blockIdx.y * 128;
    const int wm = (wave & 1) * 64, wn = (wave >> 1) * 64;
    // lane's staging source row/col (lane-order == LDS order for global_load_lds)
    const int srow = wave * 16 + (lane >> 2);
    const int scol = (lane & 3) * 8;
    const __hip_bfloat16* Ap0 = A + (size_t)(m0 + srow) * K + scol;
    const __hip_bfloat16* Ap1 = A + (size_t)(m0 + 64 + srow) * K + scol;
    const __hip_bfloat16* Bp0 = Bt + (size_t)(n0 + srow) * K + scol;
    const __hip_bfloat16* Bp1 = Bt + (size_t)(n0 + 64 + srow) * K + scol;
    __hip_bfloat16* Al0 = &As[wave * 512];
    __hip_bfloat16* Al1 = &As[2048 + wave * 512];
    __hip_bfloat16* Bl0 = &Bs[wave * 512];
    __hip_bfloat16* Bl1 = &Bs[2048 + wave * 512];
    f32x4 acc[4][4] = {};
    for (int k0 = 0; k0 < K; k0 += 32) {
        GLDS(Ap0 + k0, Al0);
        GLDS(Ap1 + k0, Al1);
        GLDS(Bp0 + k0, Bl0);
        GLDS(Bp1 + k0, Bl1);
        __syncthreads();  // drains vmcnt: LDS tiles ready
        bf16x8 af[4], bfr[4];
#pragma unroll
        for (int i = 0; i < 4; i++) {
            af[i] = *(const bf16x8*)(&As[(wm + i * 16 + l16) * 32 + quad * 8]);
            bfr[i] = *(const bf16x8*)(&Bs[(wn + i * 16 + l16) * 32 + quad * 8]);
        }
        __syncthreads();  // all frag reads done: LDS free for next staging
#pragma unroll
        for (int i = 0; i < 4; i++)
#pragma unroll
            for (int j = 0; j < 4; j++)
                acc[i][j] = MFMA16(af[i], bfr[j], acc[i][j]);
    }
    // epilogue: C row = quad*4+reg, col = l16
#pragma unroll
    for (int i = 0; i < 4; i++) {
#pragma unroll
        for (int j = 0; j < 4; j++) {
            const int mr = m0 + wm + i * 16 + quad * 4;
            const int nc = n0 + wn + j * 16 + l16;
            const float bv = bias[nc];
#pragma unroll
            for (int r = 0; r < 4; r++) {
                const float v = acc[i][j][r] + bv;
                const size_t idx = (size_t)(mr + r) * N + nc;
                if (Cf) Cf[idx] = v;
                if (Cb) Cb[idx] = __float2bfloat16(v);
            }
        }
    }
}

// ---------------------------------------------------------------------------
// Flash attention, transposed dataflow:
//   S^T = K @ Q^T   (A=K from Ks natural layout, B=Q regs)  -> col=q, row=key
//   softmax per q = per lane (in-lane reduce + 2 shuffles)
//   O^T = V^T @ P^T (A=V^T from XOR-swizzled Vs, B=P from Ps) -> col=q, row=d
// Block = 4 waves, each wave 16 q-rows; K-tile = 64 keys.
// ---------------------------------------------------------------------------
__global__ __launch_bounds__(256) void attn_kernel(
    const __hip_bfloat16* __restrict__ Qp, const __hip_bfloat16* __restrict__ Kp,
    const __hip_bfloat16* __restrict__ Vp, float* __restrict__ Op,
    int T, int Bb, int qRS, int kvRS, int causal) {
    constexpr int LDK = 72, LDV = 72, LDP = 72;
    __shared__ __align__(16) __hip_bfloat16 Ks[64 * LDK];     // [key][d]
    __shared__ __align__(16) __hip_bfloat16 Vs[64 * LDV];     // [d][key^swz]
    __shared__ __align__(16) __hip_bfloat16 Ps[4][16 * LDP];  // per-wave P[q][key]
    const int tid = threadIdx.x, wave = tid >> 6, lane = tid & 63;
    const int quad = lane >> 4, l16 = lane & 15;
    const int bh = blockIdx.y;
    const int b = bh % Bb;
    const int h = bh / Bb;
    const int q0 = blockIdx.x * 64;
    const size_t qbase = (size_t)b * qRS + h * 64;
    const size_t kbase = (size_t)b * kvRS + h * 64;
    const int qstride = Bb * qRS, kstride = Bb * kvRS;
    const size_t obase = (size_t)b * 1024 + h * 64;
    const int ostride = Bb * 1024;
    const float SC = 0.125f;  // 1/sqrt(64)

    const int myq = q0 + wave * 16 + l16;  // this lane's q-row
    bf16x8 qf0, qf1;
    {
        const __hip_bfloat16* qptr = Qp + qbase + (size_t)myq * qstride;
        qf0 = *(const bf16x8*)(qptr + quad * 8);
        qf1 = *(const bf16x8*)(qptr + 32 + quad * 8);
    }
    float m_i = -1e30f, l_i = 0.f;
    f32x4 o[4] = {};  // o[mm][r]: d = mm*16 + quad*4 + r, q = l16

    const int kend = causal ? (q0 + 64) : T;
    for (int k0 = 0; k0 < kend; k0 += 64) {
        __syncthreads();  // prior-tile Ks/Vs/Ps reads done
        {
            const int key = tid >> 2, dd = (tid & 3) * 16;
            const __hip_bfloat16* kp2 = Kp + kbase + (size_t)(k0 + key) * kstride + dd;
            *(uint4*)(&Ks[key * LDK + dd]) = *(const uint4*)(kp2);
            *(uint4*)(&Ks[key * LDK + dd + 8]) = *(const uint4*)(kp2 + 8);
            const __hip_bfloat16* vp2 = Vp + kbase + (size_t)(k0 + key) * kstride + dd;
            __align__(16) __hip_bfloat16 tmp[16];
            *(uint4*)(tmp) = *(const uint4*)(vp2);
            *(uint4*)(tmp + 8) = *(const uint4*)(vp2 + 8);
            const int kb = key >> 3, k7 = key & 7;
#pragma unroll
            for (int j = 0; j < 16; j++) {
                const int d = dd + j;
                const int blk = kb ^ ((d >> 4) << 1);  // conflict-free swizzle
                Vs[d * LDV + blk * 8 + k7] = tmp[j];
            }
        }
        __syncthreads();
        // S^T[key][q]
        f32x4 s[4];
#pragma unroll
        for (int n = 0; n < 4; n++) {
            f32x4 z = {};
            const bf16x8 kf0 = *(const bf16x8*)(&Ks[(n * 16 + l16) * LDK + quad * 8]);
            const bf16x8 kf1 = *(const bf16x8*)(&Ks[(n * 16 + l16) * LDK + 32 + quad * 8]);
            z = MFMA16(kf0, qf0, z);
            z = MFMA16(kf1, qf1, z);
            s[n] = z;
        }
        // scale + causal mask (wave-uniform branch) + per-lane max
        const bool nm = causal && (k0 + 63 > q0 + wave * 16);
        float mx = -1e30f;
#pragma unroll
        for (int n = 0; n < 4; n++) {
#pragma unroll
            for (int r = 0; r < 4; r++) {
                float sv = s[n][r] * SC;
                if (nm && (k0 + n * 16 + quad * 4 + r > myq)) sv = -1e30f;
                s[n][r] = sv;
                mx = fmaxf(mx, sv);
            }
        }
        mx = fmaxf(mx, __shfl_xor(mx, 16));
        mx = fmaxf(mx, __shfl_xor(mx, 32));
        const float mnew = fmaxf(m_i, mx);
        const float alpha = __expf(m_i - mnew);
        m_i = mnew;
        float sum = 0.f;
#pragma unroll
        for (int n = 0; n < 4; n++) {
            __align__(8) __hip_bfloat16 pb[4];
#pragma unroll
            for (int r = 0; r < 4; r++) {
                const float pv = __expf(s[n][r] - m_i);
                sum += pv;
                pb[r] = __float2bfloat16(pv);
            }
            *(uint2*)(&Ps[wave][l16 * LDP + n * 16 + quad * 4]) = *(const uint2*)pb;
        }
        sum += __shfl_xor(sum, 16);
        sum += __shfl_xor(sum, 32);
        l_i = l_i * alpha + sum;
#pragma unroll
        for (int mm = 0; mm < 4; mm++)
#pragma unroll
            for (int r = 0; r < 4; r++) o[mm][r] *= alpha;
        __syncthreads();  // Ps cross-lane visibility
        // O^T += V^T @ P^T
        const bf16x8 pf0 = *(const bf16x8*)(&Ps[wave][l16 * LDP + quad * 8]);
        const bf16x8 pf1 = *(const bf16x8*)(&Ps[wave][l16 * LDP + 32 + quad * 8]);
#pragma unroll
        for (int mm = 0; mm < 4; mm++) {
            const int blk0 = quad ^ (mm << 1);            // keys quad*8.. (chunk 0)
            const int blk1 = (4 + quad) ^ (mm << 1);      // keys 32+quad*8.. (chunk 1)
            const bf16x8 vf0 = *(const bf16x8*)(&Vs[(mm * 16 + l16) * LDV + blk0 * 8]);
            const bf16x8 vf1 = *(const bf16x8*)(&Vs[(mm * 16 + l16) * LDV + blk1 * 8]);
            o[mm] = MFMA16(vf0, pf0, o[mm]);
            o[mm] = MFMA16(vf1, pf1, o[mm]);
        }
    }
    const float inv = 1.0f / l_i;
    float* ob = Op + obase + (size_t)myq * ostride;
#pragma unroll
    for (int mm = 0; mm < 4; mm++) {
        float4 vv = make_float4(o[mm][0] * inv, o[mm][1] * inv, o[mm][2] * inv,
                                o[mm][3] * inv);
        *(float4*)(ob + mm * 16 + quad * 4) = vv;
    }
}

// ---------------------------------------------------------------------------
// Fused residual + LayerNorm over D=1024.
// ---------------------------------------------------------------------------
__global__ __launch_bounds__(256) void ln_res_kernel(
    const float* __restrict__ a, const float* __restrict__ bres,
    const float* __restrict__ g, const float* __restrict__ be,
    float* __restrict__ outf, __hip_bfloat16* __restrict__ outb) {
    const int row = blockIdx.x;
    const int tid = threadIdx.x;
    const size_t off = (size_t)row * 1024 + tid * 4;
    const float4 va = *(const float4*)(a + off);
    const float4 vb = *(const float4*)(bres + off);
    float x0 = va.x + vb.x, x1 = va.y + vb.y, x2 = va.z + vb.z, x3 = va.w + vb.w;
    float s = x0 + x1 + x2 + x3;
    float ss = x0 * x0 + x1 * x1 + x2 * x2 + x3 * x3;
#pragma unroll
    for (int w = 32; w >= 1; w >>= 1) {
        s += __shfl_xor(s, w);
        ss += __shfl_xor(ss, w);
    }
    __shared__ float sm[4], sv[4];
    const int wave = tid >> 6;
    if ((tid & 63) == 0) { sm[wave] = s; sv[wave] = ss; }
    __syncthreads();
    s = sm[0] + sm[1] + sm[2] + sm[3];
    ss = sv[0] + sv[1] + sv[2] + sv[3];
    const float mean = s * (1.f / 1024.f);
    const float inv = rsqrtf(ss * (1.f / 1024.f) - mean * mean + 1e-5f);
    const float4 gg = *(const float4*)(g + tid * 4);
    const float4 bb = *(const float4*)(be + tid * 4);
    const float y0 = (x0 - mean) * inv * gg.x + bb.x;
    const float y1 = (x1 - mean) * inv * gg.y + bb.y;
    const float y2 = (x2 - mean) * inv * gg.z + bb.z;
    const float y3 = (x3 - mean) * inv * gg.w + bb.w;
    *(float4*)(outf + off) = make_float4(y0, y1, y2, y3);
    if (outb) {
        __align__(8) __hip_bfloat16 t[4] = {__float2bfloat16(y0), __float2bfloat16(y1),
                                            __float2bfloat16(y2), __float2bfloat16(y3)};
        *(uint2*)(outb + off) = *(const uint2*)t;
    }
}

// ---------------------------------------------------------------------------
extern "C" void kernel_launch(void* const* d_in, const int* in_sizes, int n_in,
                              void* d_out, int out_size, void* d_ws, size_t ws_size,
                              hipStream_t stream) {
    const float* enc = (const float*)d_in[0];
    const float* dec = (const float*)d_in[1];
    const float* Wq1 = (const float*)d_in[2];
    const float* bq1 = (const float*)d_in[3];
    const float* Wk1 = (const float*)d_in[4];
    const float* bk1 = (const float*)d_in[5];
    const float* Wv1 = (const float*)d_in[6];
    const float* bv1 = (const float*)d_in[7];
    const float* Wq2 = (const float*)d_in[8];
    const float* bq2 = (const float*)d_in[9];
    const float* Wk2 = (const float*)d_in[10];
    const float* bk2 = (const float*)d_in[11];
    const float* Wv2 = (const float*)d_in[12];
    const float* bv2 = (const float*)d_in[13];
    const float* Wl = (const float*)d_in[14];
    const float* bl = (const float*)d_in[15];
    const float* g1 = (const float*)d_in[16];
    const float* be1 = (const float*)d_in[17];
    const float* g2 = (const float*)d_in[18];
    const float* be2 = (const float*)d_in[19];
    const float* g3 = (const float*)d_in[20];
    const float* be3 = (const float*)d_in[21];
    float* outp = (float*)d_out;

    char* p = (char*)d_ws;
    auto alloc = [&](size_t n) {
        char* r = p;
        p += (n + 255) & ~(size_t)255;
        return r;
    };
    const size_t MD = (size_t)8192 * 1024;
    __hip_bfloat16* enc_b = (__hip_bfloat16*)alloc(MD * 2);
    __hip_bfloat16* dec_b = (__hip_bfloat16*)alloc(MD * 2);
    __hip_bfloat16* Wt = (__hip_bfloat16*)alloc((size_t)7 * 1024 * 1024 * 2);
    float* bcat = (float*)alloc((3072 + 2048) * sizeof(float));
    __hip_bfloat16* qkv = (__hip_bfloat16*)alloc(MD * 3 * 2);  // also reused as KV2
    __hip_bfloat16* qb = (__hip_bfloat16*)alloc(MD * 2);
    float* attnf = (float*)alloc(MD * 4);
    float* xf = (float*)alloc(MD * 4);
    float* yf = (float*)alloc(MD * 4);
    __hip_bfloat16* xb = dec_b;  // dec_b dead after QKV1 gemm
    __hip_bfloat16* yb = enc_b;  // enc_b dead after KV2 gemm

    const float* Ws[7] = {Wq1, Wk1, Wv1, Wq2, Wk2, Wv2, Wl};
    for (int i = 0; i < 7; i++) {
        wt_transpose<<<dim3(32, 32), dim3(32, 8), 0, stream>>>(
            Ws[i], Wt + (size_t)i * 1024 * 1024, 1024, 1024);
    }
    to_bf16<<<8192, 256, 0, stream>>>(enc, enc_b, (int)MD);
    to_bf16<<<8192, 256, 0, stream>>>(dec, dec_b, (int)MD);
    hipMemcpyAsync(bcat, bq1, 4096, hipMemcpyDeviceToDevice, stream);
    hipMemcpyAsync(bcat + 1024, bk1, 4096, hipMemcpyDeviceToDevice, stream);
    hipMemcpyAsync(bcat + 2048, bv1, 4096, hipMemcpyDeviceToDevice, stream);
    hipMemcpyAsync(bcat + 3072, bk2, 4096, hipMemcpyDeviceToDevice, stream);
    hipMemcpyAsync(bcat + 4096, bv2, 4096, hipMemcpyDeviceToDevice, stream);

    // --- self-attention ---
    gemm_bias_kernel<<<dim3(64, 24), 256, 0, stream>>>(dec_b, Wt, bcat, nullptr, qkv,
                                                       8192, 3072, 1024);
    attn_kernel<<<dim3(16, 128), 256, 0, stream>>>(qkv, qkv + 1024, qkv + 2048, attnf,
                                                   1024, 8, 3072, 3072, 1);
    ln_res_kernel<<<8192, 256, 0, stream>>>(attnf, dec, g1, be1, xf, xb);

    // --- cross-attention ---
    gemm_bias_kernel<<<dim3(64, 8), 256, 0, stream>>>(
        xb, Wt + (size_t)3 * 1024 * 1024, bq2, nullptr, qb, 8192, 1024, 1024);
    gemm_bias_kernel<<<dim3(64, 16), 256, 0, stream>>>(
        enc_b, Wt + (size_t)4 * 1024 * 1024, bcat + 3072, nullptr, qkv, 8192, 2048, 1024);
    attn_kernel<<<dim3(16, 128), 256, 0, stream>>>(qb, qkv, qkv + 1024, attnf,
                                                   1024, 8, 1024, 2048, 0);
    ln_res_kernel<<<8192, 256, 0, stream>>>(attnf, xf, g2, be2, yf, yb);

    // --- position-wise linear ---
    gemm_bias_kernel<<<dim3(64, 8), 256, 0, stream>>>(
        yb, Wt + (size_t)6 * 1024 * 1024, bl, attnf, nullptr, 8192, 1024, 1024);
    ln_res_kernel<<<8192, 256, 0, stream>>>(attnf, yf, g3, be3, outp, nullptr);
}

// Round 3
// 576.722 us; speedup vs baseline: 1.2358x; 1.0441x over previous
//
#include <hip/hip_runtime.h>
#include <hip/hip_bf16.h>

typedef __bf16 bf16x8 __attribute__((ext_vector_type(8)));
typedef float f32x4 __attribute__((ext_vector_type(4)));

#define MFMA16(A, B, C) __builtin_amdgcn_mfma_f32_16x16x32_bf16(A, B, C, 0, 0, 0)

// async global->LDS, 16B per lane. LDS dest = wave-uniform base + lane*16.
#define GLDS(gp, lp)                                                              \
    __builtin_amdgcn_global_load_lds(                                             \
        (const __attribute__((address_space(1))) void*)(gp),                      \
        (__attribute__((address_space(3))) void*)(lp), 16, 0, 0)

// ---------------------------------------------------------------------------
// Fused weight transpose + fp32->bf16 for all 7 weights: W[K,N] -> Wt[N,K]
// grid (32, 32, 7), block (32, 8)
// ---------------------------------------------------------------------------
struct PtrW { const float* p[7]; };
__global__ __launch_bounds__(256) void wt_transpose(PtrW W, __hip_bfloat16* __restrict__ Wt) {
    const float* __restrict__ src = W.p[blockIdx.z];
    __hip_bfloat16* __restrict__ dst = Wt + ((size_t)blockIdx.z << 20);
    __shared__ float tile[32][33];
    const int bn = blockIdx.x * 32;
    const int bk = blockIdx.y * 32;
    const int tx = threadIdx.x, ty = threadIdx.y;
#pragma unroll
    for (int i = 0; i < 4; i++) {
        tile[ty + i * 8][tx] = src[(size_t)(bk + ty + i * 8) * 1024 + bn + tx];
    }
    __syncthreads();
#pragma unroll
    for (int i = 0; i < 4; i++) {
        dst[(size_t)(bn + ty + i * 8) * 1024 + bk + tx] =
            __float2bfloat16(tile[tx][ty + i * 8]);
    }
}

// fp32 -> bf16, two tensors fused; grid (8192, 2)
struct PtrC { const float* s[2]; __hip_bfloat16* d[2]; };
__global__ __launch_bounds__(256) void to_bf16(PtrC c) {
    const int z = blockIdx.y;
    const int i = (blockIdx.x * 256 + threadIdx.x) * 4;
    const float4 v = *(const float4*)(c.s[z] + i);
    __align__(8) __hip_bfloat16 t[4] = {__float2bfloat16(v.x), __float2bfloat16(v.y),
                                        __float2bfloat16(v.z), __float2bfloat16(v.w)};
    *(uint2*)(c.d[z] + i) = *(const uint2*)t;
}

// concat 5 bias vectors (1024 each) into dst; grid 5, block 256
struct Ptr5 { const float* p[5]; };
__global__ __launch_bounds__(256) void bias_concat(Ptr5 srcs, float* __restrict__ dst) {
    const int i = threadIdx.x * 4;
    *(float4*)(dst + blockIdx.x * 1024 + i) = *(const float4*)(srcs.p[blockIdx.x] + i);
}

// ---------------------------------------------------------------------------
// V transpose per (b,h): src rows m=t*8+b (row length S, col offset passed via
// caller ptr+coloff) -> Vt[(b*16+h)][d(64)][t(1024)] bf16. grid (16, 128).
// ---------------------------------------------------------------------------
__global__ __launch_bounds__(256) void v_transpose(const __hip_bfloat16* __restrict__ src,
                                                   __hip_bfloat16* __restrict__ Vt,
                                                   int S, int coloff) {
    __shared__ __hip_bfloat16 tile[64][72];
    const int t0 = blockIdx.x * 64;
    const int bh = blockIdx.y;
    const int b = bh & 7, h = bh >> 3;
    const int tid = threadIdx.x;
    const int r = tid >> 2, c = (tid & 3) * 16;
    const __hip_bfloat16* sp =
        src + (size_t)((t0 + r) * 8 + b) * S + coloff + h * 64 + c;
    *(uint4*)(&tile[r][c]) = *(const uint4*)(sp);
    *(uint4*)(&tile[r][c + 8]) = *(const uint4*)(sp + 8);
    __syncthreads();
    const int d = tid >> 2, tc = (tid & 3) * 16;
    __align__(16) __hip_bfloat16 tmp[16];
#pragma unroll
    for (int j = 0; j < 16; j++) tmp[j] = tile[tc + j][d];
    __hip_bfloat16* op = Vt + ((size_t)(b * 16 + h) << 16) + (size_t)d * 1024 + t0 + tc;
    *(uint4*)(op) = *(const uint4*)(tmp);
    *(uint4*)(op + 8) = *(const uint4*)(tmp + 8);
}

// ---------------------------------------------------------------------------
// GEMM: C[M,N] = A[M,K] @ Bt[N,K]^T + bias. bf16 in, MFMA 16x16x32.
// 128x128 tile, 4 waves 2x2, BK=64, GLDS width16, XOR-swizzled 64-col LDS rows.
// ---------------------------------------------------------------------------
__global__ __launch_bounds__(256) void gemm_bias_kernel(
    const __hip_bfloat16* __restrict__ A, const __hip_bfloat16* __restrict__ Bt,
    const float* __restrict__ bias, float* __restrict__ Cf,
    __hip_bfloat16* __restrict__ Cb, int M, int N, int K) {
    __shared__ __align__(16) __hip_bfloat16 As[128 * 64];
    __shared__ __align__(16) __hip_bfloat16 Bs[128 * 64];
    const int tid = threadIdx.x;
    const int wave = tid >> 6, lane = tid & 63;
    const int quad = lane >> 4, l16 = lane & 15;
    const int m0 = blockIdx.x * 128, n0 = blockIdx.y * 128;
    const int wm = (wave & 1) * 64, wn = (wave >> 1) * 64;
    const int lrow = lane >> 3;
    const int lch = (lane & 7) ^ (lrow & 7);  // source-side XOR swizzle
    const int sw = l16 & 7;
    const __hip_bfloat16* ap[4];
    const __hip_bfloat16* bp[4];
    __hip_bfloat16* al[4];
    __hip_bfloat16* bl[4];
#pragma unroll
    for (int u = 0; u < 4; u++) {
        const int q = wave * 4 + u;  // instr q covers rows q*8..q*8+7
        const int row = q * 8 + lrow;
        ap[u] = A + (size_t)(m0 + row) * K + lch * 8;
        bp[u] = Bt + (size_t)(n0 + row) * K + lch * 8;
        al[u] = &As[q * 512];
        bl[u] = &Bs[q * 512];
    }
    f32x4 acc[4][4] = {};
    for (int k0 = 0; k0 < K; k0 += 64) {
#pragma unroll
        for (int u = 0; u < 4; u++) {
            GLDS(ap[u] + k0, al[u]);
            GLDS(bp[u] + k0, bl[u]);
        }
        __syncthreads();  // staging complete (drains vmcnt)
        bf16x8 af[2][4], bfr[2][4];
#pragma unroll
        for (int h2 = 0; h2 < 2; h2++)
#pragma unroll
            for (int i = 0; i < 4; i++) {
                af[h2][i] = *(const bf16x8*)(&As[(wm + i * 16 + l16) * 64 +
                                                 (((h2 * 4 + quad) ^ sw) << 3)]);
                bfr[h2][i] = *(const bf16x8*)(&Bs[(wn + i * 16 + l16) * 64 +
                                                  (((h2 * 4 + quad) ^ sw) << 3)]);
            }
        __syncthreads();  // all frag reads done: LDS free for next GLDS
#pragma unroll
        for (int h2 = 0; h2 < 2; h2++)
#pragma unroll
            for (int i = 0; i < 4; i++)
#pragma unroll
                for (int j = 0; j < 4; j++)
                    acc[i][j] = MFMA16(af[h2][i], bfr[h2][j], acc[i][j]);
    }
    // epilogue: C row = quad*4+reg, col = l16
#pragma unroll
    for (int i = 0; i < 4; i++) {
#pragma unroll
        for (int j = 0; j < 4; j++) {
            const int mr = m0 + wm + i * 16 + quad * 4;
            const int nc = n0 + wn + j * 16 + l16;
            const float bv = bias[nc];
#pragma unroll
            for (int r = 0; r < 4; r++) {
                const float v = acc[i][j][r] + bv;
                const size_t idx = (size_t)(mr + r) * N + nc;
                if (Cf) Cf[idx] = v;
                if (Cb) Cb[idx] = __float2bfloat16(v);
            }
        }
    }
}

// ---------------------------------------------------------------------------
// Flash attention (transposed dataflow), GLDS-staged K and pre-transposed V.
//   S^T = K @ Q^T, per-lane softmax (q = l16), O^T = V^T @ P^T.
// K source: rows t (stride 8*kRS), V source: Vt[(b*16+h)][d][t].
// Output Ob bf16 [8192][1024]. grid (T/64, 128).
// ---------------------------------------------------------------------------
__global__ __launch_bounds__(256) void attn_kernel(
    const __hip_bfloat16* __restrict__ Qp, const __hip_bfloat16* __restrict__ Kp,
    const __hip_bfloat16* __restrict__ Vt, __hip_bfloat16* __restrict__ Ob,
    int T, int qRS, int kRS, int causal) {
    __shared__ __align__(16) __hip_bfloat16 Ks[64 * 64];
    __shared__ __align__(16) __hip_bfloat16 Vs[64 * 64];
    __shared__ __align__(16) __hip_bfloat16 Ps[4][16 * 64];
    const int tid = threadIdx.x, wave = tid >> 6, lane = tid & 63;
    const int quad = lane >> 4, l16 = lane & 15;
    const int bh = blockIdx.y, b = bh & 7, h = bh >> 3;
    const int q0 = blockIdx.x * 64;
    const int qstride = 8 * qRS, kstride = 8 * kRS;
    const int sw = l16 & 7;
    const float SCL = 0.18033688f;  // (1/8) * log2(e): softmax in exp2 domain

    const int myq = q0 + wave * 16 + l16;
    bf16x8 qf0, qf1;
    {
        const __hip_bfloat16* qptr = Qp + (size_t)b * qRS + h * 64 + (size_t)myq * qstride;
        qf0 = *(const bf16x8*)(qptr + quad * 8);
        qf1 = *(const bf16x8*)(qptr + 32 + quad * 8);
    }
    // GLDS staging: wave w stages K rows [w*16, w*16+16) and V rows likewise
    const int jk = wave * 2;
    const int lrow = lane >> 3;
    const int lch = (lane & 7) ^ (lrow & 7);
    const __hip_bfloat16* kp0 =
        Kp + (size_t)b * kRS + h * 64 + (size_t)(jk * 8 + lrow) * kstride + lch * 8;
    const __hip_bfloat16* kp1 = kp0 + (size_t)8 * kstride;
    const __hip_bfloat16* vp0 =
        Vt + ((size_t)(b * 16 + h) << 16) + (size_t)(jk * 8 + lrow) * 1024 + lch * 8;
    const __hip_bfloat16* vp1 = vp0 + 8 * 1024;
    __hip_bfloat16* kl0 = &Ks[jk * 512];
    __hip_bfloat16* kl1 = &Ks[jk * 512 + 512];
    __hip_bfloat16* vl0 = &Vs[jk * 512];
    __hip_bfloat16* vl1 = &Vs[jk * 512 + 512];

    float m_i = -1e30f, l_i = 0.f;
    f32x4 o[4] = {};  // o[mm][r]: d = mm*16 + quad*4 + r, q = l16
    const int kend = causal ? (q0 + 64) : T;
    for (int k0 = 0; k0 < kend; k0 += 64) {
        __syncthreads();  // all waves done reading prior Ks/Vs
        GLDS(kp0 + (size_t)k0 * kstride, kl0);
        GLDS(kp1 + (size_t)k0 * kstride, kl1);
        GLDS(vp0 + k0, vl0);
        GLDS(vp1 + k0, vl1);
        __syncthreads();  // staging complete
        // S^T[key][q]
        f32x4 s[4];
#pragma unroll
        for (int n = 0; n < 4; n++) {
            f32x4 z = {};
            const int row = (n * 16 + l16) * 64;
            const bf16x8 kf0 = *(const bf16x8*)(&Ks[row + ((quad ^ sw) << 3)]);
            const bf16x8 kf1 = *(const bf16x8*)(&Ks[row + (((quad + 4) ^ sw) << 3)]);
            z = MFMA16(kf0, qf0, z);
            z = MFMA16(kf1, qf1, z);
            s[n] = z;
        }
        const bool nm = causal && (k0 + 63 > q0 + wave * 16);
        float mx = -1e30f;
#pragma unroll
        for (int n = 0; n < 4; n++) {
#pragma unroll
            for (int r = 0; r < 4; r++) {
                float sv = s[n][r] * SCL;
                if (nm && (k0 + n * 16 + quad * 4 + r > myq)) sv = -1e30f;
                s[n][r] = sv;
                mx = fmaxf(mx, sv);
            }
        }
        mx = fmaxf(mx, __shfl_xor(mx, 16));
        mx = fmaxf(mx, __shfl_xor(mx, 32));
        const float mnew = fmaxf(m_i, mx);
        const float alpha = exp2f(m_i - mnew);
        m_i = mnew;
        float sum = 0.f;
#pragma unroll
        for (int n = 0; n < 4; n++) {
            __align__(8) __hip_bfloat16 pb[4];
#pragma unroll
            for (int r = 0; r < 4; r++) {
                const float pv = exp2f(s[n][r] - m_i);
                sum += pv;
                pb[r] = __float2bfloat16(pv);
            }
            const int gcp = 2 * n + (quad >> 1);
            *(uint2*)(&Ps[wave][l16 * 64 + ((gcp ^ sw) << 3) + (quad & 1) * 4]) =
                *(const uint2*)pb;
        }
        sum += __shfl_xor(sum, 16);
        sum += __shfl_xor(sum, 32);
        l_i = l_i * alpha + sum;
#pragma unroll
        for (int mm = 0; mm < 4; mm++) o[mm] = o[mm] * alpha;
        // Ps written+read by same wave only: compiler inserts lgkmcnt wait
        const bf16x8 pf0 = *(const bf16x8*)(&Ps[wave][l16 * 64 + ((quad ^ sw) << 3)]);
        const bf16x8 pf1 =
            *(const bf16x8*)(&Ps[wave][l16 * 64 + (((quad + 4) ^ sw) << 3)]);
#pragma unroll
        for (int mm = 0; mm < 4; mm++) {
            const int vrow = (mm * 16 + l16) * 64;
            const bf16x8 vf0 = *(const bf16x8*)(&Vs[vrow + ((quad ^ sw) << 3)]);
            const bf16x8 vf1 = *(const bf16x8*)(&Vs[vrow + (((quad + 4) ^ sw) << 3)]);
            o[mm] = MFMA16(vf0, pf0, o[mm]);
            o[mm] = MFMA16(vf1, pf1, o[mm]);
        }
    }
    const float inv = 1.0f / l_i;
    __hip_bfloat16* ob = Ob + (size_t)b * 1024 + h * 64 + (size_t)myq * 8192;
#pragma unroll
    for (int mm = 0; mm < 4; mm++) {
        __align__(8) __hip_bfloat16 t[4] = {
            __float2bfloat16(o[mm][0] * inv), __float2bfloat16(o[mm][1] * inv),
            __float2bfloat16(o[mm][2] * inv), __float2bfloat16(o[mm][3] * inv)};
        *(uint2*)(ob + mm * 16 + quad * 4) = *(const uint2*)t;
    }
}

// ---------------------------------------------------------------------------
// Fused residual + LayerNorm over D=1024. a is bf16, residual fp32.
// ---------------------------------------------------------------------------
__global__ __launch_bounds__(256) void ln_res_kernel(
    const __hip_bfloat16* __restrict__ a, const float* __restrict__ bres,
    const float* __restrict__ g, const float* __restrict__ be,
    float* __restrict__ outf, __hip_bfloat16* __restrict__ outb) {
    const int row = blockIdx.x;
    const int tid = threadIdx.x;
    const size_t off = (size_t)row * 1024 + tid * 4;
    uint2 ar = *(const uint2*)(a + off);
    const __hip_bfloat16* ah = (const __hip_bfloat16*)&ar;
    const float4 vb = *(const float4*)(bres + off);
    float x0 = __bfloat162float(ah[0]) + vb.x;
    float x1 = __bfloat162float(ah[1]) + vb.y;
    float x2 = __bfloat162float(ah[2]) + vb.z;
    float x3 = __bfloat162float(ah[3]) + vb.w;
    float s = x0 + x1 + x2 + x3;
    float ss = x0 * x0 + x1 * x1 + x2 * x2 + x3 * x3;
#pragma unroll
    for (int w = 32; w >= 1; w >>= 1) {
        s += __shfl_xor(s, w);
        ss += __shfl_xor(ss, w);
    }
    __shared__ float sm[4], sv[4];
    const int wave = tid >> 6;
    if ((tid & 63) == 0) { sm[wave] = s; sv[wave] = ss; }
    __syncthreads();
    s = sm[0] + sm[1] + sm[2] + sm[3];
    ss = sv[0] + sv[1] + sv[2] + sv[3];
    const float mean = s * (1.f / 1024.f);
    const float inv = rsqrtf(ss * (1.f / 1024.f) - mean * mean + 1e-5f);
    const float4 gg = *(const float4*)(g + tid * 4);
    const float4 bb = *(const float4*)(be + tid * 4);
    const float y0 = (x0 - mean) * inv * gg.x + bb.x;
    const float y1 = (x1 - mean) * inv * gg.y + bb.y;
    const float y2 = (x2 - mean) * inv * gg.z + bb.z;
    const float y3 = (x3 - mean) * inv * gg.w + bb.w;
    if (outf) *(float4*)(outf + off) = make_float4(y0, y1, y2, y3);
    if (outb) {
        __align__(8) __hip_bfloat16 t[4] = {__float2bfloat16(y0), __float2bfloat16(y1),
                                            __float2bfloat16(y2), __float2bfloat16(y3)};
        *(uint2*)(outb + off) = *(const uint2*)t;
    }
}

// ---------------------------------------------------------------------------
extern "C" void kernel_launch(void* const* d_in, const int* in_sizes, int n_in,
                              void* d_out, int out_size, void* d_ws, size_t ws_size,
                              hipStream_t stream) {
    const float* enc = (const float*)d_in[0];
    const float* dec = (const float*)d_in[1];
    const float* Wq1 = (const float*)d_in[2];
    const float* bq1 = (const float*)d_in[3];
    const float* Wk1 = (const float*)d_in[4];
    const float* bk1 = (const float*)d_in[5];
    const float* Wv1 = (const float*)d_in[6];
    const float* bv1 = (const float*)d_in[7];
    const float* Wq2 = (const float*)d_in[8];
    const float* bq2 = (const float*)d_in[9];
    const float* Wk2 = (const float*)d_in[10];
    const float* bk2 = (const float*)d_in[11];
    const float* Wv2 = (const float*)d_in[12];
    const float* bv2 = (const float*)d_in[13];
    const float* Wl = (const float*)d_in[14];
    const float* bl = (const float*)d_in[15];
    const float* g1 = (const float*)d_in[16];
    const float* be1 = (const float*)d_in[17];
    const float* g2 = (const float*)d_in[18];
    const float* be2 = (const float*)d_in[19];
    const float* g3 = (const float*)d_in[20];
    const float* be3 = (const float*)d_in[21];
    float* outp = (float*)d_out;

    char* p = (char*)d_ws;
    auto alloc = [&](size_t n) {
        char* r = p;
        p += (n + 255) & ~(size_t)255;
        return r;
    };
    const size_t MD = (size_t)8192 * 1024;
    __hip_bfloat16* enc_b = (__hip_bfloat16*)alloc(MD * 2);
    __hip_bfloat16* dec_b = (__hip_bfloat16*)alloc(MD * 2);
    __hip_bfloat16* Wt = (__hip_bfloat16*)alloc((size_t)7 * 1024 * 1024 * 2);
    float* bcat = (float*)alloc((3072 + 2048) * sizeof(float));
    __hip_bfloat16* qkv = (__hip_bfloat16*)alloc(MD * 3 * 2);  // also reused as KV2
    __hip_bfloat16* qb = (__hip_bfloat16*)alloc(MD * 2);       // q2; reused as z
    __hip_bfloat16* attnb = (__hip_bfloat16*)alloc(MD * 2);    // attn outputs (bf16)
    __hip_bfloat16* Vtb = (__hip_bfloat16*)alloc(MD * 2);      // transposed V planes
    float* xf = (float*)alloc(MD * 4);
    float* yf = (float*)alloc(MD * 4);
    __hip_bfloat16* xb = dec_b;  // dec_b dead after QKV1 gemm
    __hip_bfloat16* yb = enc_b;  // enc_b dead after KV2 gemm

    PtrW wptrs = {{Wq1, Wk1, Wv1, Wq2, Wk2, Wv2, Wl}};
    wt_transpose<<<dim3(32, 32, 7), dim3(32, 8), 0, stream>>>(wptrs, Wt);
    PtrC cp = {{enc, dec}, {enc_b, dec_b}};
    to_bf16<<<dim3(8192, 2), 256, 0, stream>>>(cp);
    Ptr5 bp = {{bq1, bk1, bv1, bk2, bv2}};
    bias_concat<<<5, 256, 0, stream>>>(bp, bcat);

    // --- self-attention ---
    gemm_bias_kernel<<<dim3(64, 24), 256, 0, stream>>>(dec_b, Wt, bcat, nullptr, qkv,
                                                       8192, 3072, 1024);
    v_transpose<<<dim3(16, 128), 256, 0, stream>>>(qkv, Vtb, 3072, 2048);
    attn_kernel<<<dim3(16, 128), 256, 0, stream>>>(qkv, qkv + 1024, Vtb, attnb,
                                                   1024, 3072, 3072, 1);
    ln_res_kernel<<<8192, 256, 0, stream>>>(attnb, dec, g1, be1, xf, xb);

    // --- cross-attention ---
    gemm_bias_kernel<<<dim3(64, 8), 256, 0, stream>>>(
        xb, Wt + (size_t)3 * 1024 * 1024, bq2, nullptr, qb, 8192, 1024, 1024);
    gemm_bias_kernel<<<dim3(64, 16), 256, 0, stream>>>(
        enc_b, Wt + (size_t)4 * 1024 * 1024, bcat + 3072, nullptr, qkv, 8192, 2048, 1024);
    v_transpose<<<dim3(16, 128), 256, 0, stream>>>(qkv, Vtb, 2048, 1024);
    attn_kernel<<<dim3(16, 128), 256, 0, stream>>>(qb, qkv, Vtb, attnb,
                                                   1024, 1024, 2048, 0);
    ln_res_kernel<<<8192, 256, 0, stream>>>(attnb, xf, g2, be2, yf, yb);

    // --- position-wise linear ---
    gemm_bias_kernel<<<dim3(64, 8), 256, 0, stream>>>(
        yb, Wt + (size_t)6 * 1024 * 1024, bl, nullptr, qb, 8192, 1024, 1024);
    ln_res_kernel<<<8192, 256, 0, stream>>>(qb, yf, g3, be3, outp, nullptr);
}

// Round 4
// 543.324 us; speedup vs baseline: 1.3118x; 1.0615x over previous
//
#include <hip/hip_runtime.h>
#include <hip/hip_bf16.h>

typedef __bf16 bf16x8 __attribute__((ext_vector_type(8)));
typedef float f32x4 __attribute__((ext_vector_type(4)));

#define MFMA16(A, B, C) __builtin_amdgcn_mfma_f32_16x16x32_bf16(A, B, C, 0, 0, 0)

// async global->LDS, 16B per lane. LDS dest = wave-uniform base + lane*16.
#define GLDS(gp, lp)                                                              \
    __builtin_amdgcn_global_load_lds(                                             \
        (const __attribute__((address_space(1))) void*)(gp),                      \
        (__attribute__((address_space(3))) void*)(lp), 16, 0, 0)

// ---------------------------------------------------------------------------
// Fused weight transpose + fp32->bf16 for all 7 weights: W[K,N] -> Wt[N,K]
// ---------------------------------------------------------------------------
struct PtrW { const float* p[7]; };
__global__ __launch_bounds__(256) void wt_transpose(PtrW W, __hip_bfloat16* __restrict__ Wt) {
    const float* __restrict__ src = W.p[blockIdx.z];
    __hip_bfloat16* __restrict__ dst = Wt + ((size_t)blockIdx.z << 20);
    __shared__ float tile[32][33];
    const int bn = blockIdx.x * 32;
    const int bk = blockIdx.y * 32;
    const int tx = threadIdx.x, ty = threadIdx.y;
#pragma unroll
    for (int i = 0; i < 4; i++) {
        tile[ty + i * 8][tx] = src[(size_t)(bk + ty + i * 8) * 1024 + bn + tx];
    }
    __syncthreads();
#pragma unroll
    for (int i = 0; i < 4; i++) {
        dst[(size_t)(bn + ty + i * 8) * 1024 + bk + tx] =
            __float2bfloat16(tile[tx][ty + i * 8]);
    }
}

struct PtrC { const float* s[2]; __hip_bfloat16* d[2]; };
__global__ __launch_bounds__(256) void to_bf16(PtrC c) {
    const int z = blockIdx.y;
    const int i = (blockIdx.x * 256 + threadIdx.x) * 4;
    const float4 v = *(const float4*)(c.s[z] + i);
    __align__(8) __hip_bfloat16 t[4] = {__float2bfloat16(v.x), __float2bfloat16(v.y),
                                        __float2bfloat16(v.z), __float2bfloat16(v.w)};
    *(uint2*)(c.d[z] + i) = *(const uint2*)t;
}

struct Ptr5 { const float* p[5]; };
__global__ __launch_bounds__(256) void bias_concat(Ptr5 srcs, float* __restrict__ dst) {
    const int i = threadIdx.x * 4;
    *(float4*)(dst + blockIdx.x * 1024 + i) = *(const float4*)(srcs.p[blockIdx.x] + i);
}

// ---------------------------------------------------------------------------
// V transpose per (b,h): src [t*8+b][S] (+coloff+h*64) -> Vt[(b*16+h)][d][t]
// ---------------------------------------------------------------------------
__global__ __launch_bounds__(256) void v_transpose(const __hip_bfloat16* __restrict__ src,
                                                   __hip_bfloat16* __restrict__ Vt,
                                                   int S, int coloff) {
    __shared__ __hip_bfloat16 tile[64][72];
    const int t0 = blockIdx.x * 64;
    const int bh = blockIdx.y;
    const int b = bh & 7, h = bh >> 3;
    const int tid = threadIdx.x;
    const int r = tid >> 2, c = (tid & 3) * 16;
    const __hip_bfloat16* sp =
        src + (size_t)((t0 + r) * 8 + b) * S + coloff + h * 64 + c;
    *(uint4*)(&tile[r][c]) = *(const uint4*)(sp);
    *(uint4*)(&tile[r][c + 8]) = *(const uint4*)(sp + 8);
    __syncthreads();
    const int d = tid >> 2, tc = (tid & 3) * 16;
    __align__(16) __hip_bfloat16 tmp[16];
#pragma unroll
    for (int j = 0; j < 16; j++) tmp[j] = tile[tc + j][d];
    __hip_bfloat16* op = Vt + ((size_t)(b * 16 + h) << 16) + (size_t)d * 1024 + t0 + tc;
    *(uint4*)(op) = *(const uint4*)(tmp);
    *(uint4*)(op + 8) = *(const uint4*)(tmp + 8);
}

// ---------------------------------------------------------------------------
// GEMM: C[M,N] = A[M,K] @ Bt[N,K]^T + bias, optional per-column scale.
// 128x128 tile, 4 waves 2x2, BK=32, double-buffered GLDS, 1 barrier/step.
// LDS rows 32 cols, physical chunk p = logical ^ ((row>>1)&3) -> 2-way free.
// ---------------------------------------------------------------------------
__global__ __launch_bounds__(256) void gemm_bias_kernel(
    const __hip_bfloat16* __restrict__ A, const __hip_bfloat16* __restrict__ Bt,
    const float* __restrict__ bias, float* __restrict__ Cf,
    __hip_bfloat16* __restrict__ Cb, int M, int N, int K,
    float qscale, int qcols) {
    __shared__ __align__(16) __hip_bfloat16 As[2][128 * 32];
    __shared__ __align__(16) __hip_bfloat16 Bs[2][128 * 32];
    const int tid = threadIdx.x;
    const int wave = tid >> 6, lane = tid & 63;
    const int quad = lane >> 4, l16 = lane & 15;
    const int m0 = blockIdx.x * 128, n0 = blockIdx.y * 128;
    const int wm = (wave & 1) * 64, wn = (wave >> 1) * 64;
    // staging: GLDS group g = wave*2+u covers rows g*16..g*16+15 (32 cols)
    const int srow = lane >> 2;
    const int lc = (lane & 3) ^ ((lane >> 3) & 3);  // logical chunk to fetch
    const __hip_bfloat16* ap[2];
    const __hip_bfloat16* bp[2];
    int loff[2];
#pragma unroll
    for (int u = 0; u < 2; u++) {
        const int g = wave * 2 + u;
        const int row = g * 16 + srow;
        ap[u] = A + (size_t)(m0 + row) * K + lc * 8;
        bp[u] = Bt + (size_t)(n0 + row) * K + lc * 8;
        loff[u] = g * 512;
    }
    const int pch = quad ^ ((l16 >> 1) & 3);  // physical chunk for frag reads
    f32x4 acc[4][4] = {};
#pragma unroll
    for (int u = 0; u < 2; u++) {
        GLDS(ap[u], &As[0][loff[u]]);
        GLDS(bp[u], &Bs[0][loff[u]]);
    }
    int sel = 0;
    for (int k0 = 0; k0 < K; k0 += 32) {
        __syncthreads();  // buf[sel] staged; prior reads of buf[sel^1] done
        if (k0 + 32 < K) {
#pragma unroll
            for (int u = 0; u < 2; u++) {
                GLDS(ap[u] + k0 + 32, &As[sel ^ 1][loff[u]]);
                GLDS(bp[u] + k0 + 32, &Bs[sel ^ 1][loff[u]]);
            }
        }
        bf16x8 af[4], bfr[4];
#pragma unroll
        for (int i = 0; i < 4; i++) {
            af[i] = *(const bf16x8*)(&As[sel][(wm + i * 16 + l16) * 32 + pch * 8]);
            bfr[i] = *(const bf16x8*)(&Bs[sel][(wn + i * 16 + l16) * 32 + pch * 8]);
        }
#pragma unroll
        for (int i = 0; i < 4; i++)
#pragma unroll
            for (int j = 0; j < 4; j++)
                acc[i][j] = MFMA16(af[i], bfr[j], acc[i][j]);
        sel ^= 1;
    }
    // epilogue: C row = quad*4+reg, col = l16
#pragma unroll
    for (int i = 0; i < 4; i++) {
#pragma unroll
        for (int j = 0; j < 4; j++) {
            const int mr = m0 + wm + i * 16 + quad * 4;
            const int nc = n0 + wn + j * 16 + l16;
            const float sc = (nc < qcols) ? qscale : 1.0f;
            const float bv = bias[nc];
#pragma unroll
            for (int r = 0; r < 4; r++) {
                const float v = (acc[i][j][r] + bv) * sc;
                const size_t idx = (size_t)(mr + r) * N + nc;
                if (Cf) Cf[idx] = v;
                if (Cb) Cb[idx] = __float2bfloat16(v);
            }
        }
    }
}

// ---------------------------------------------------------------------------
// Flash attention, transposed dataflow, double-buffered K/V (1 barrier/tile),
// XCD-swizzled grid, sum-of-exp via ones-row MFMA, Q pre-scaled by GEMM.
//   S^T = K @ Q^T  (q = l16 per lane), O^T = V^T @ P^T.
// grid: 2048 1-D blocks (128 bh x 16 q-tiles), block 256.
// ---------------------------------------------------------------------------
__global__ __launch_bounds__(256) void attn_kernel(
    const __hip_bfloat16* __restrict__ Qp, const __hip_bfloat16* __restrict__ Kp,
    const __hip_bfloat16* __restrict__ Vt, __hip_bfloat16* __restrict__ Ob,
    int T, int qRS, int kRS, int causal) {
    __shared__ __align__(16) __hip_bfloat16 Ks[2][64 * 64];
    __shared__ __align__(16) __hip_bfloat16 Vs[2][64 * 64];
    __shared__ __align__(16) __hip_bfloat16 Ps[4][16 * 64];
    const int tid = threadIdx.x, wave = tid >> 6, lane = tid & 63;
    const int quad = lane >> 4, l16 = lane & 15;
    // XCD-aware swizzle: 16 bh per XCD so K/V stay resident in that XCD's L2
    const int gid = blockIdx.x;
    const int bh = (gid & 7) * 16 + (gid >> 7);
    const int qt = (gid >> 3) & 15;
    const int b = bh & 7, h = bh >> 3;
    const int q0 = qt * 64;
    const int qstride = 8 * qRS, kstride = 8 * kRS;
    const int sw = l16 & 7;

    const int myq = q0 + wave * 16 + l16;
    bf16x8 qf0, qf1;
    {
        const __hip_bfloat16* qptr = Qp + (size_t)b * qRS + h * 64 + (size_t)myq * qstride;
        qf0 = *(const bf16x8*)(qptr + quad * 8);
        qf1 = *(const bf16x8*)(qptr + 32 + quad * 8);
    }
    bf16x8 onesf;
#pragma unroll
    for (int i = 0; i < 8; i++) onesf[i] = (__bf16)1.0f;

    // staging duty: wave stages GLDS groups jk, jk+1 (8 rows x 64 cols each)
    const int jk = wave * 2;
    const int lrow = lane >> 3;
    const int lch = (lane & 7) ^ (lrow & 7);
    const __hip_bfloat16* kp0 =
        Kp + (size_t)b * kRS + h * 64 + (size_t)(jk * 8 + lrow) * kstride + lch * 8;
    const __hip_bfloat16* kp1 = kp0 + (size_t)8 * kstride;
    const __hip_bfloat16* vp0 =
        Vt + ((size_t)(b * 16 + h) << 16) + (size_t)(jk * 8 + lrow) * 1024 + lch * 8;
    const __hip_bfloat16* vp1 = vp0 + 8 * 1024;
    const size_t kinc = (size_t)64 * kstride;

    float m_i = -1e30f;
    f32x4 o[4] = {};   // o[mm][r]: d = mm*16 + quad*4 + r, q = l16
    f32x4 ol = {};     // ones-row accumulator: every entry = sum_k exp(...)
    const int kend = causal ? (q0 + 64) : T;
    const int qmax_w = q0 + wave * 16 + 15;  // this wave's largest q row

    // prologue: stage tile 0 into buffer 0
    GLDS(kp0, &Ks[0][jk * 512]);
    GLDS(kp1, &Ks[0][jk * 512 + 512]);
    GLDS(vp0, &Vs[0][jk * 512]);
    GLDS(vp1, &Vs[0][jk * 512 + 512]);
    const __hip_bfloat16* kn0 = kp0 + kinc;
    const __hip_bfloat16* kn1 = kp1 + kinc;
    const __hip_bfloat16* vn0 = vp0 + 64;
    const __hip_bfloat16* vn1 = vp1 + 64;
    int sel = 0;
    for (int k0 = 0; k0 < kend; k0 += 64) {
        __syncthreads();  // buf[sel] staged (vmcnt drained); reads of buf[sel^1] done
        if (k0 + 64 < kend) {
            GLDS(kn0, &Ks[sel ^ 1][jk * 512]);
            GLDS(kn1, &Ks[sel ^ 1][jk * 512 + 512]);
            GLDS(vn0, &Vs[sel ^ 1][jk * 512]);
            GLDS(vn1, &Vs[sel ^ 1][jk * 512 + 512]);
            kn0 += kinc; kn1 += kinc; vn0 += 64; vn1 += 64;
        }
        // skip fully-masked tiles (wave-uniform): all keys > all q of this wave
        if (!causal || k0 <= qmax_w) {
            // S^T[key][q]
            f32x4 s[4];
#pragma unroll
            for (int n = 0; n < 4; n++) {
                f32x4 z = {};
                const int row = (n * 16 + l16) * 64;
                const bf16x8 kf0 = *(const bf16x8*)(&Ks[sel][row + ((quad ^ sw) << 3)]);
                const bf16x8 kf1 =
                    *(const bf16x8*)(&Ks[sel][row + (((quad + 4) ^ sw) << 3)]);
                z = MFMA16(kf0, qf0, z);
                z = MFMA16(kf1, qf1, z);
                s[n] = z;
            }
            const bool nm = causal && (k0 + 63 > q0 + wave * 16);
            float mx = -1e30f;
            if (nm) {
#pragma unroll
                for (int n = 0; n < 4; n++)
#pragma unroll
                    for (int r = 0; r < 4; r++) {
                        if (k0 + n * 16 + quad * 4 + r > myq) s[n][r] = -1e30f;
                        mx = fmaxf(mx, s[n][r]);
                    }
            } else {
#pragma unroll
                for (int n = 0; n < 4; n++)
#pragma unroll
                    for (int r = 0; r < 4; r++) mx = fmaxf(mx, s[n][r]);
            }
            mx = fmaxf(mx, __shfl_xor(mx, 16));
            mx = fmaxf(mx, __shfl_xor(mx, 32));
            const float mnew = fmaxf(m_i, mx);
            const float alpha = exp2f(m_i - mnew);
            m_i = mnew;
#pragma unroll
            for (int n = 0; n < 4; n++) {
                const float p0 = exp2f(s[n][0] - m_i);
                const float p1 = exp2f(s[n][1] - m_i);
                const float p2 = exp2f(s[n][2] - m_i);
                const float p3 = exp2f(s[n][3] - m_i);
                const __hip_bfloat162 pa = __float22bfloat162_rn(make_float2(p0, p1));
                const __hip_bfloat162 pb = __float22bfloat162_rn(make_float2(p2, p3));
                uint2 w;
                w.x = *(const unsigned int*)&pa;
                w.y = *(const unsigned int*)&pb;
                const int gcp = 2 * n + (quad >> 1);
                *(uint2*)(&Ps[wave][l16 * 64 + ((gcp ^ sw) << 3) + (quad & 1) * 4]) = w;
            }
#pragma unroll
            for (int mm = 0; mm < 4; mm++) o[mm] = o[mm] * alpha;
            ol = ol * alpha;
            // same-wave Ps write->read: compiler inserts lgkmcnt wait
            const bf16x8 pf0 = *(const bf16x8*)(&Ps[wave][l16 * 64 + ((quad ^ sw) << 3)]);
            const bf16x8 pf1 =
                *(const bf16x8*)(&Ps[wave][l16 * 64 + (((quad + 4) ^ sw) << 3)]);
#pragma unroll
            for (int mm = 0; mm < 4; mm++) {
                const int vrow = (mm * 16 + l16) * 64;
                const bf16x8 vf0 = *(const bf16x8*)(&Vs[sel][vrow + ((quad ^ sw) << 3)]);
                const bf16x8 vf1 =
                    *(const bf16x8*)(&Vs[sel][vrow + (((quad + 4) ^ sw) << 3)]);
                o[mm] = MFMA16(vf0, pf0, o[mm]);
                o[mm] = MFMA16(vf1, pf1, o[mm]);
            }
            ol = MFMA16(onesf, pf0, ol);
            ol = MFMA16(onesf, pf1, ol);
        }
        sel ^= 1;
    }
    const float inv = 1.0f / ol[0];
    __hip_bfloat16* ob = Ob + (size_t)b * 1024 + h * 64 + (size_t)myq * 8192;
#pragma unroll
    for (int mm = 0; mm < 4; mm++) {
        __align__(8) __hip_bfloat16 t[4] = {
            __float2bfloat16(o[mm][0] * inv), __float2bfloat16(o[mm][1] * inv),
            __float2bfloat16(o[mm][2] * inv), __float2bfloat16(o[mm][3] * inv)};
        *(uint2*)(ob + mm * 16 + quad * 4) = *(const uint2*)t;
    }
}

// ---------------------------------------------------------------------------
// Fused residual + LayerNorm over D=1024. a is bf16, residual fp32.
// ---------------------------------------------------------------------------
__global__ __launch_bounds__(256) void ln_res_kernel(
    const __hip_bfloat16* __restrict__ a, const float* __restrict__ bres,
    const float* __restrict__ g, const float* __restrict__ be,
    float* __restrict__ outf, __hip_bfloat16* __restrict__ outb) {
    const int row = blockIdx.x;
    const int tid = threadIdx.x;
    const size_t off = (size_t)row * 1024 + tid * 4;
    uint2 ar = *(const uint2*)(a + off);
    const __hip_bfloat16* ah = (const __hip_bfloat16*)&ar;
    const float4 vb = *(const float4*)(bres + off);
    float x0 = __bfloat162float(ah[0]) + vb.x;
    float x1 = __bfloat162float(ah[1]) + vb.y;
    float x2 = __bfloat162float(ah[2]) + vb.z;
    float x3 = __bfloat162float(ah[3]) + vb.w;
    float s = x0 + x1 + x2 + x3;
    float ss = x0 * x0 + x1 * x1 + x2 * x2 + x3 * x3;
#pragma unroll
    for (int w = 32; w >= 1; w >>= 1) {
        s += __shfl_xor(s, w);
        ss += __shfl_xor(ss, w);
    }
    __shared__ float sm[4], sv[4];
    const int wave = tid >> 6;
    if ((tid & 63) == 0) { sm[wave] = s; sv[wave] = ss; }
    __syncthreads();
    s = sm[0] + sm[1] + sm[2] + sm[3];
    ss = sv[0] + sv[1] + sv[2] + sv[3];
    const float mean = s * (1.f / 1024.f);
    const float inv = rsqrtf(ss * (1.f / 1024.f) - mean * mean + 1e-5f);
    const float4 gg = *(const float4*)(g + tid * 4);
    const float4 bb = *(const float4*)(be + tid * 4);
    const float y0 = (x0 - mean) * inv * gg.x + bb.x;
    const float y1 = (x1 - mean) * inv * gg.y + bb.y;
    const float y2 = (x2 - mean) * inv * gg.z + bb.z;
    const float y3 = (x3 - mean) * inv * gg.w + bb.w;
    if (outf) *(float4*)(outf + off) = make_float4(y0, y1, y2, y3);
    if (outb) {
        __align__(8) __hip_bfloat16 t[4] = {__float2bfloat16(y0), __float2bfloat16(y1),
                                            __float2bfloat16(y2), __float2bfloat16(y3)};
        *(uint2*)(outb + off) = *(const uint2*)t;
    }
}

// ---------------------------------------------------------------------------
extern "C" void kernel_launch(void* const* d_in, const int* in_sizes, int n_in,
                              void* d_out, int out_size, void* d_ws, size_t ws_size,
                              hipStream_t stream) {
    const float* enc = (const float*)d_in[0];
    const float* dec = (const float*)d_in[1];
    const float* Wq1 = (const float*)d_in[2];
    const float* bq1 = (const float*)d_in[3];
    const float* Wk1 = (const float*)d_in[4];
    const float* bk1 = (const float*)d_in[5];
    const float* Wv1 = (const float*)d_in[6];
    const float* bv1 = (const float*)d_in[7];
    const float* Wq2 = (const float*)d_in[8];
    const float* bq2 = (const float*)d_in[9];
    const float* Wk2 = (const float*)d_in[10];
    const float* bk2 = (const float*)d_in[11];
    const float* Wv2 = (const float*)d_in[12];
    const float* bv2 = (const float*)d_in[13];
    const float* Wl = (const float*)d_in[14];
    const float* bl = (const float*)d_in[15];
    const float* g1 = (const float*)d_in[16];
    const float* be1 = (const float*)d_in[17];
    const float* g2 = (const float*)d_in[18];
    const float* be2 = (const float*)d_in[19];
    const float* g3 = (const float*)d_in[20];
    const float* be3 = (const float*)d_in[21];
    float* outp = (float*)d_out;

    char* p = (char*)d_ws;
    auto alloc = [&](size_t n) {
        char* r = p;
        p += (n + 255) & ~(size_t)255;
        return r;
    };
    const size_t MD = (size_t)8192 * 1024;
    __hip_bfloat16* enc_b = (__hip_bfloat16*)alloc(MD * 2);
    __hip_bfloat16* dec_b = (__hip_bfloat16*)alloc(MD * 2);
    __hip_bfloat16* Wt = (__hip_bfloat16*)alloc((size_t)7 * 1024 * 1024 * 2);
    float* bcat = (float*)alloc((3072 + 2048) * sizeof(float));
    __hip_bfloat16* qkv = (__hip_bfloat16*)alloc(MD * 3 * 2);  // also reused as KV2
    __hip_bfloat16* qb = (__hip_bfloat16*)alloc(MD * 2);       // q2; reused as z
    __hip_bfloat16* attnb = (__hip_bfloat16*)alloc(MD * 2);    // attn outputs (bf16)
    __hip_bfloat16* Vtb = (__hip_bfloat16*)alloc(MD * 2);      // transposed V planes
    float* xf = (float*)alloc(MD * 4);
    float* yf = (float*)alloc(MD * 4);
    __hip_bfloat16* xb = dec_b;  // dec_b dead after QKV1 gemm
    __hip_bfloat16* yb = enc_b;  // enc_b dead after KV2 gemm

    const float QSC = 0.18033688f;  // (1/sqrt(64)) * log2(e): softmax in exp2 domain

    PtrW wptrs = {{Wq1, Wk1, Wv1, Wq2, Wk2, Wv2, Wl}};
    wt_transpose<<<dim3(32, 32, 7), dim3(32, 8), 0, stream>>>(wptrs, Wt);
    PtrC cp = {{enc, dec}, {enc_b, dec_b}};
    to_bf16<<<dim3(8192, 2), 256, 0, stream>>>(cp);
    Ptr5 bp = {{bq1, bk1, bv1, bk2, bv2}};
    bias_concat<<<5, 256, 0, stream>>>(bp, bcat);

    // --- self-attention ---
    gemm_bias_kernel<<<dim3(64, 24), 256, 0, stream>>>(dec_b, Wt, bcat, nullptr, qkv,
                                                       8192, 3072, 1024, QSC, 1024);
    v_transpose<<<dim3(16, 128), 256, 0, stream>>>(qkv, Vtb, 3072, 2048);
    attn_kernel<<<2048, 256, 0, stream>>>(qkv, qkv + 1024, Vtb, attnb,
                                          1024, 3072, 3072, 1);
    ln_res_kernel<<<8192, 256, 0, stream>>>(attnb, dec, g1, be1, xf, xb);

    // --- cross-attention ---
    gemm_bias_kernel<<<dim3(64, 8), 256, 0, stream>>>(
        xb, Wt + (size_t)3 * 1024 * 1024, bq2, nullptr, qb, 8192, 1024, 1024, QSC, 1024);
    gemm_bias_kernel<<<dim3(64, 16), 256, 0, stream>>>(
        enc_b, Wt + (size_t)4 * 1024 * 1024, bcat + 3072, nullptr, qkv, 8192, 2048, 1024,
        1.0f, 0);
    v_transpose<<<dim3(16, 128), 256, 0, stream>>>(qkv, Vtb, 2048, 1024);
    attn_kernel<<<2048, 256, 0, stream>>>(qb, qkv, Vtb, attnb, 1024, 1024, 2048, 0);
    ln_res_kernel<<<8192, 256, 0, stream>>>(attnb, xf, g2, be2, yf, yb);

    // --- position-wise linear ---
    gemm_bias_kernel<<<dim3(64, 8), 256, 0, stream>>>(
        yb, Wt + (size_t)6 * 1024 * 1024, bl, nullptr, qb, 8192, 1024, 1024, 1.0f, 0);
    ln_res_kernel<<<8192, 256, 0, stream>>>(qb, yf, g3, be3, outp, nullptr);
}